// Round 1
// 798.615 us; speedup vs baseline: 1.0127x; 1.0127x over previous
//
#include <hip/hip_runtime.h>
#include <stdint.h>

// ---------------------------------------------------------------------------
// TopicRNN_GCN: h = lrelu(adj @ lrelu(adj @ (maxgather(emb) @ W1) + b1) @ W2 + b2)
//
// This round: remove convert_adj entirely. The two big adj GEMMs read fp32 adj
// DIRECTLY (reg-staged, on-the-fly bf16 convert, ds_write), with full-N 64x256
// tiles (grid y=1) so adj is fetched exactly once per GEMM:
//   adj traffic: 400r+203w + 2x406r (old) -> 2x400r (now).
// Small GEMMs keep the verified m97-style bf16 gemm_bt path.
// ---------------------------------------------------------------------------

#define N_NODES 10000
#define MP      10112          // M padded to 158*64
#define KP      10048          // adj K padded to multiple of 64
#define EMB     300
#define EKP     320            // embed K padded
#define HID     256
#define SLOPE   0.01f

typedef __attribute__((ext_vector_type(8))) short          bf16x8;
typedef __attribute__((ext_vector_type(4))) float          f32x4;
typedef __attribute__((ext_vector_type(8))) unsigned short ushort8;
typedef __attribute__((ext_vector_type(4))) unsigned short ushort4v;

__device__ __forceinline__ unsigned short f2b(float f) {
    union { float f; unsigned u; } v; v.f = f;
    unsigned r = v.u + 0x7FFFu + ((v.u >> 16) & 1u);   // round-nearest-even
    return (unsigned short)(r >> 16);
}

__device__ __forceinline__ void g2l16(const void* gptr, const void* ldsptr) {
    __builtin_amdgcn_global_load_lds(
        (const __attribute__((address_space(1))) void*)(uintptr_t)gptr,
        (__attribute__((address_space(3))) void*)(uint32_t)(uintptr_t)ldsptr,
        16, 0, 0);
}

// ---------------------------------------------------------------------------
// x[i][e] = max_r emb[nodes[(i+1)*8+r]][e]  -> bf16 (MP x EKP), zero-padded
__global__ void gather_max_x(const int* __restrict__ nodes,
                             const float* __restrict__ emb,
                             unsigned short* __restrict__ xb) {
    const int i = blockIdx.x;
    unsigned short* xrow = xb + (size_t)i * EKP;
    if (i >= N_NODES) {
        for (int e = threadIdx.x; e < EKP; e += 256) xrow[e] = 0;
        return;
    }
    const int* idx = nodes + (i + 1) * 8;
    int id[8];
#pragma unroll
    for (int r = 0; r < 8; ++r) id[r] = idx[r];
    for (int e = threadIdx.x; e < EKP; e += 256) {
        unsigned short v = 0;
        if (e < EMB) {
            float m = emb[(size_t)id[0] * EMB + e];
#pragma unroll
            for (int r = 1; r < 8; ++r) m = fmaxf(m, emb[(size_t)id[r] * EMB + e]);
            v = f2b(m);
        }
        xrow[e] = v;
    }
}

// W (K x 256) fp32 -> Wt (256 x Kpad) bf16, zero-padded
__global__ void prep_w(const float* __restrict__ W, unsigned short* __restrict__ Wt,
                       int K, int Kpad) {
    const int o = blockIdx.x * 256 + threadIdx.x;
    if (o >= HID * Kpad) return;
    const int n = o / Kpad, k = o % Kpad;
    Wt[o] = (k < K) ? f2b(W[(size_t)k * HID + n]) : 0;
}

// bf16 transpose: in (>=KP rows x 256) -> out (256 x KP)
__global__ void transpose_bf16(const unsigned short* __restrict__ in,
                               unsigned short* __restrict__ out) {
    __shared__ unsigned short t[32][33];
    const int kt = blockIdx.x * 32, nt = blockIdx.y * 32;
    const int x = threadIdx.x, y0 = threadIdx.y;
#pragma unroll
    for (int yy = y0; yy < 32; yy += 8)
        t[yy][x] = in[(size_t)(kt + yy) * HID + nt + x];
    __syncthreads();
#pragma unroll
    for (int yy = y0; yy < 32; yy += 8)
        out[(size_t)(nt + yy) * KP + kt + x] = t[x][yy];
}

// ---------------------------------------------------------------------------
// MFMA GEMM for the small matmuls (bf16 A, bf16 Bt), 128x128 tile, BK=64,
// 4 waves (each 64x64 = 4x4 of 16x16x32).  Writes bf16 C (M x ldC).
__launch_bounds__(256, 3)
__global__ void gemm_bt(const unsigned short* __restrict__ A, int ldA,
                        const unsigned short* __restrict__ Bt, int ldB,
                        unsigned short* __restrict__ C, int ldC, int Ktot) {
    const int tid  = threadIdx.x;
    const int wave = tid >> 6, lane = tid & 63;
    const int wm = wave >> 1, wn = wave & 1;
    const int l16 = lane & 15, quad = lane >> 4;
    const int tileM = blockIdx.x * 128;
    const int tileN = blockIdx.y * 128;

    __shared__ unsigned short ldsA[128 * 64];
    __shared__ unsigned short ldsB[128 * 64];

    const unsigned short* Ag = A  + (size_t)(tileM + (tid >> 3)) * ldA + ((tid & 7) * 8);
    const unsigned short* Bg = Bt + (size_t)(tileN + (tid >> 3)) * ldB + ((tid & 7) * 8);
    unsigned short* lA = &ldsA[tid * 8];
    unsigned short* lB = &ldsB[tid * 8];
    const size_t aStep = (size_t)32 * ldA;
    const size_t bStep = (size_t)32 * ldB;

    const unsigned short* pa0 = &ldsA[(wm * 64 + l16) * 64 + quad * 8];
    const unsigned short* pb0 = &ldsB[(wn * 64 + l16) * 64 + quad * 8];

    f32x4 acc[4][4] = {};
    const int kIters = Ktot >> 6;

    for (int kt = 0; kt < kIters; ++kt) {
        __syncthreads();
#pragma unroll
        for (int i = 0; i < 4; ++i) {
            g2l16(Ag + i * aStep, lA + i * 2048);
            g2l16(Bg + i * bStep, lB + i * 2048);
        }
        Ag += 64; Bg += 64;
        __syncthreads();
#pragma unroll
        for (int kk = 0; kk < 64; kk += 32) {
            bf16x8 af[4], bq[4];
#pragma unroll
            for (int i = 0; i < 4; ++i) af[i] = *(const bf16x8*)(pa0 + i * 1024 + kk);
#pragma unroll
            for (int j = 0; j < 4; ++j) bq[j] = *(const bf16x8*)(pb0 + j * 1024 + kk);
#pragma unroll
            for (int i = 0; i < 4; ++i)
#pragma unroll
                for (int j = 0; j < 4; ++j)
                    acc[i][j] = __builtin_amdgcn_mfma_f32_16x16x32_bf16(
                        af[i], bq[j], acc[i][j], 0, 0, 0);
        }
    }

#pragma unroll
    for (int i = 0; i < 4; ++i)
#pragma unroll
        for (int r = 0; r < 4; ++r) {
            const int row = tileM + wm * 64 + i * 16 + quad * 4 + r;
#pragma unroll
            for (int j = 0; j < 4; ++j) {
                const int col = tileN + wn * 64 + j * 16 + l16;
                C[(size_t)row * ldC + col] = f2b(acc[i][j][r]);
            }
        }
}

// ---------------------------------------------------------------------------
// adj-GEMM: A = fp32 adj (10000 x 10000), read DIRECTLY with on-the-fly bf16
// convert (reg-staged A -> LDS); B = bf16 Bt (256 x KP) via global_load_lds.
// Tile 64 x 256 (full N in one block -> adj fetched exactly once per GEMM),
// 4 waves (each 64x64), split-K over blockIdx.z; fp32 partials out.
// LDS = 8KB (A) + 32KB (B) = 40KB -> 3 blocks/CU; 632 blocks all co-resident.
__launch_bounds__(256, 3)
__global__ void gemm_adj_f32(const float* __restrict__ A,
                             const unsigned short* __restrict__ Bt,
                             float* __restrict__ parts,
                             int kChunk, size_t partStride) {
    const int tid  = threadIdx.x;
    const int wave = tid >> 6, lane = tid & 63;
    const int l16 = lane & 15, quad = lane >> 4;
    const int tileM  = blockIdx.x * 64;
    const int kStart = (int)blockIdx.z * kChunk;
    const int kLen   = min(kChunk, KP - kStart);
    const int kIters = kLen >> 6;

    __shared__ unsigned short ldsA[64 * 64];     // bf16 A tile
    __shared__ unsigned short ldsB[256 * 64];    // bf16 B tile (full N)

    // A staging map: round r in {0,1}: row = (tid>>3) + r*32, cols (tid&7)*8..+8
    const int arow = tid >> 3;                   // 0..31
    const int acol = (tid & 7) * 8;              // 0..56

    // B staging: 8 rounds of global_load_lds(16B), linear LDS layout [256][64]
    const unsigned short* Bg = Bt + (size_t)(tid >> 3) * KP + kStart + acol;
    unsigned short* lB = &ldsB[tid * 8];

    const unsigned short* pa0 = &ldsA[l16 * 64 + quad * 8];
    const unsigned short* pb0 = &ldsB[(wave * 64 + l16) * 64 + quad * 8];

    f32x4 acc[4][4] = {};

    // fp32 A prefetch registers (2 rounds x 8 floats)
    f32x4 av[2][2];

    auto loadA = [&](int kt) {
#pragma unroll
        for (int r = 0; r < 2; ++r) {
            const int grow = tileM + arow + r * 32;
            const int gc   = kStart + kt * 64 + acol;
            if (grow < N_NODES && gc + 8 <= N_NODES) {
                const float* src = A + (size_t)grow * N_NODES + gc;
                av[r][0] = *(const f32x4*)src;
                av[r][1] = *(const f32x4*)(src + 4);
            } else if (grow < N_NODES) {
#pragma unroll
                for (int h = 0; h < 2; ++h)
#pragma unroll
                    for (int t = 0; t < 4; ++t)
                        av[r][h][t] = (gc + h * 4 + t < N_NODES)
                                    ? A[(size_t)grow * N_NODES + gc + h * 4 + t] : 0.0f;
            } else {
                av[r][0] = (f32x4){0.f, 0.f, 0.f, 0.f};
                av[r][1] = (f32x4){0.f, 0.f, 0.f, 0.f};
            }
        }
    };

    loadA(0);

    for (int kt = 0; kt < kIters; ++kt) {
        __syncthreads();                     // prev-tile consumers done; A regs ready
        // convert + ds_write A
#pragma unroll
        for (int r = 0; r < 2; ++r) {
            ushort8 o;
#pragma unroll
            for (int h = 0; h < 2; ++h)
#pragma unroll
            for (int t = 0; t < 4; ++t) o[h * 4 + t] = f2b(av[r][h][t]);
            *(ushort8*)(&ldsA[(arow + r * 32) * 64 + acol]) = o;
        }
        // B tile: 256 rows x 64 cols, 8 rounds of 32 rows
        const unsigned short* bg = Bg + kt * 64;
#pragma unroll
        for (int i = 0; i < 8; ++i)
            g2l16(bg + (size_t)i * 32 * KP, lB + i * 2048);
        __syncthreads();                     // tile ready (drains B g2l16 + ds_write)
        if (kt + 1 < kIters) loadA(kt + 1);  // A(kt+1) in flight during MFMA phase
#pragma unroll
        for (int kk = 0; kk < 64; kk += 32) {
            bf16x8 af[4], bq[4];
#pragma unroll
            for (int i = 0; i < 4; ++i) af[i] = *(const bf16x8*)(pa0 + i * 1024 + kk);
#pragma unroll
            for (int j = 0; j < 4; ++j) bq[j] = *(const bf16x8*)(pb0 + j * 1024 + kk);
#pragma unroll
            for (int i = 0; i < 4; ++i)
#pragma unroll
                for (int j = 0; j < 4; ++j)
                    acc[i][j] = __builtin_amdgcn_mfma_f32_16x16x32_bf16(
                        af[i], bq[j], acc[i][j], 0, 0, 0);
        }
    }

    float* C = parts + (size_t)blockIdx.z * partStride;
#pragma unroll
    for (int i = 0; i < 4; ++i)
#pragma unroll
        for (int r = 0; r < 4; ++r) {
            const int row = tileM + i * 16 + quad * 4 + r;
#pragma unroll
            for (int j = 0; j < 4; ++j) {
                const int col = wave * 64 + j * 16 + l16;
                C[(size_t)row * HID + col] = acc[i][j][r];
            }
        }
}

// sum 4 split-K partials + bias, leaky-relu; OUT_BF16: bf16 (all MP rows),
// else fp32 to d_out (rows < outRows only).
template <int OUT_BF16>
__global__ void reduce_bias_lrelu(const float* __restrict__ parts, size_t partStride,
                                  const float* __restrict__ bias,
                                  void* __restrict__ out, int outRows) {
    const int idx = blockIdx.x * 256 + threadIdx.x;
    const int e4  = idx * 4;
    const int row = e4 >> 8;
    const int col = e4 & 255;
    if (row >= MP) return;
    f32x4 s = *(const f32x4*)(parts + e4);
#pragma unroll
    for (int p = 1; p < 4; ++p) s += *(const f32x4*)(parts + p * partStride + e4);
    s += *(const f32x4*)(bias + col);
#pragma unroll
    for (int t = 0; t < 4; ++t) s[t] = s[t] > 0.0f ? s[t] : SLOPE * s[t];
    if (OUT_BF16) {
        ushort4v o;
#pragma unroll
        for (int t = 0; t < 4; ++t) o[t] = f2b(s[t]);
        *(ushort4v*)((unsigned short*)out + e4) = o;
    } else if (row < outRows) {
        *(f32x4*)((float*)out + e4) = s;
    }
}

// ---------------------------------------------------------------------------
extern "C" void kernel_launch(void* const* d_in, const int* in_sizes, int n_in,
                              void* d_out, int out_size, void* d_ws, size_t ws_size,
                              hipStream_t stream) {
    const int*   nodes = (const int*)d_in[0];
    const float* emb   = (const float*)d_in[1];
    const float* adj   = (const float*)d_in[2];
    const float* W1    = (const float*)d_in[3];
    const float* b1    = (const float*)d_in[4];
    const float* W2    = (const float*)d_in[5];
    const float* b2    = (const float*)d_in[6];

    char* ws = (char*)d_ws;
    size_t o = 0;
    unsigned short* xb   = (unsigned short*)(ws + o); o += (size_t)MP * EKP * 2;  // 6.5 MB
    unsigned short* w1t  = (unsigned short*)(ws + o); o += (size_t)HID * EKP * 2;
    unsigned short* w2t  = (unsigned short*)(ws + o); o += (size_t)HID * HID * 2;
    unsigned short* u1   = (unsigned short*)(ws + o); o += (size_t)MP * HID * 2;
    unsigned short* u1t  = (unsigned short*)(ws + o); o += (size_t)HID * KP * 2;
    unsigned short* h1   = (unsigned short*)(ws + o); o += (size_t)MP * HID * 2;
    unsigned short* u2   = (unsigned short*)(ws + o); o += (size_t)MP * HID * 2;
    unsigned short* u2t  = (unsigned short*)(ws + o); o += (size_t)HID * KP * 2;
    float*          parts= (float*)(ws + o);          o += (size_t)4 * MP * HID * 4; // 41.4 MB

    const size_t PSTRIDE = (size_t)MP * HID;   // elements per split partial

    // 0) gather + weight prep (no adj conversion pass anymore)
    gather_max_x<<<MP, 256, 0, stream>>>(nodes, emb, xb);
    prep_w      <<<(HID * EKP + 255) / 256, 256, 0, stream>>>(W1, w1t, EMB, EKP);
    prep_w      <<<(HID * HID + 255) / 256, 256, 0, stream>>>(W2, w2t, HID, HID);

    // 1) u1 = x @ W1    (M x 256)
    gemm_bt<<<dim3(79, 2), 256, 0, stream>>>(xb, EKP, w1t, EKP, u1, HID, EKP);
    transpose_bf16<<<dim3(KP / 32, HID / 32), dim3(32, 8), 0, stream>>>(u1, u1t);

    // 2) h1 = lrelu(adj @ u1 + b1)   fp32-adj direct, split-K=4
    gemm_adj_f32<<<dim3(158, 1, 4), 256, 0, stream>>>(adj, u1t, parts, 2560, PSTRIDE);
    reduce_bias_lrelu<1><<<(MP * HID / 4 + 255) / 256, 256, 0, stream>>>(
        parts, PSTRIDE, b1, h1, MP);

    // 3) u2 = h1 @ W2
    gemm_bt<<<dim3(79, 2), 256, 0, stream>>>(h1, HID, w2t, HID, u2, HID, HID);
    transpose_bf16<<<dim3(KP / 32, HID / 32), dim3(32, 8), 0, stream>>>(u2, u2t);

    // 4) out = lrelu(adj @ u2 + b2)  fp32-adj direct, split-K=4, fp32 out
    gemm_adj_f32<<<dim3(158, 1, 4), 256, 0, stream>>>(adj, u2t, parts, 2560, PSTRIDE);
    reduce_bias_lrelu<0><<<(MP * HID / 4 + 255) / 256, 256, 0, stream>>>(
        parts, PSTRIDE, b2, d_out, N_NODES);
}